// Round 20
// baseline (69.816 us; speedup 1.0000x reference)
//
#include <hip/hip_runtime.h>

#define LOG2E 1.4426950408889634f
#define TWO_LOG2E 2.885390081777927f

__device__ __forceinline__ float fast_exp2(float x) { return __builtin_amdgcn_exp2f(x); }
__device__ __forceinline__ float fast_rcp(float x)  { return __builtin_amdgcn_rcpf(x); }

// paired-rcp: s0/A + s1/B with A=q0*k0+1, B=q1*k1+1
__device__ __forceinline__ void term2(float s0, float s1, float qx, float qy,
                                      float kx, float ky, float& acc) {
    const float A = fmaf(qx, kx, 1.f);
    const float B = fmaf(qy, ky, 1.f);
    acc = fmaf(fmaf(s1, A, s0 * B), fast_rcp(A * B), acc);
}

// ---------------------------------------------------------------------------
// K1: projections + exp transform (unchanged, proven).
// ---------------------------------------------------------------------------
__global__ __launch_bounds__(256) void proj_kernel(
    const float* __restrict__ query, const float* __restrict__ value,
    const float* __restrict__ Wq, const float* __restrict__ Wv,
    float* __restrict__ eq, float* __restrict__ ek)
{
    __shared__ float in_lds[8 * 256];
    const int t = threadIdx.x;
    const int row0 = blockIdx.x * 8;
    const float* src; const float* W; float* dst;
    if (row0 < 2048) { src = query + (size_t)row0 * 256; W = Wq; dst = eq + (size_t)row0 * 256; }
    else { const int r = row0 - 2048; src = value + (size_t)r * 256; W = Wv; dst = ek + (size_t)r * 256; }

    const float4* s4 = (const float4*)src;
    float4* l4 = (float4*)in_lds;
    l4[t] = s4[t];
    l4[t + 256] = s4[t + 256];
    __syncthreads();

    float acc[8];
#pragma unroll
    for (int r = 0; r < 8; ++r) acc[r] = 0.f;

    for (int d = 0; d < 256; d += 4) {
        const float w0 = W[(d + 0) * 256 + t];
        const float w1 = W[(d + 1) * 256 + t];
        const float w2 = W[(d + 2) * 256 + t];
        const float w3 = W[(d + 3) * 256 + t];
#pragma unroll
        for (int r = 0; r < 8; ++r) {
            const float4 v = *(const float4*)&in_lds[r * 256 + d];
            acc[r] = fmaf(v.x, w0, acc[r]);
            acc[r] = fmaf(v.y, w1, acc[r]);
            acc[r] = fmaf(v.z, w2, acc[r]);
            acc[r] = fmaf(v.w, w3, acc[r]);
        }
    }
#pragma unroll
    for (int r = 0; r < 8; ++r) dst[r * 256 + t] = fast_exp2(acc[r] * TWO_LOG2E);
}

// ---------------------------------------------------------------------------
// K2: FUSED scores + softmax + PV, v7: 4q x 4k register tile.
// Block = (b, 8 q-rows), 1024 thr (16 waves), grid (64,4) = 256 blocks.
// Wave w = (oct = w>>1: 32-d octant, qh = w&1: which 4 q-rows).
// Lane = (dd = lane>>4: 8-d subsector, kq = lane&15: k-quad).
// Per 4-d it: 1 sc + 4 q + 4 k = 9 b128 per 64 elems (was 7 per 32) and each
// k value read 2x (was 4x) -> Phase A LDS issue cut ~35%. VALU unchanged.
// dd-combine: 2 shfl_xor per acc (in-register). pslot rows stride 68 ->
// 4 b128 partial-writes at 2-way banks (free). T14 global prefetch + rotate
// swizzle (0 conflicts, R13) + softmax/PV/reduce carried from R16.
// ---------------------------------------------------------------------------
#define EK_ST 260
#define EQ_ST 260
#define SS_ST 520
#define PSQ_ST 68
#define PSO_ST (8 * PSQ_ST)
__global__ __launch_bounds__(1024, 4) void fused_kernel(
    const float* __restrict__ eq, const float* __restrict__ ek,
    const float* __restrict__ scale, const float* __restrict__ value,
    float* __restrict__ attn, float* __restrict__ out)
{
    __shared__ float ek_lds[64 * EK_ST];    // 66.6KB; reduce buffer in Phase D
    __shared__ float eq_lds[8 * EQ_ST];     // 8.3KB
    __shared__ float sc_lds[256];
    __shared__ float s_tile[8 * SS_ST];     // 16.6KB raw scores -> raw exp
    __shared__ float pslot[8 * PSO_ST];     // 17.4KB octant partials
    __shared__ float inv_lds[8];

    const int t = threadIdx.x;
    const int w = t >> 6, lane = t & 63;
    const int oct = w >> 1, qh = w & 1;
    const int dd = lane >> 4, kq = lane & 15;
    const int qt = blockIdx.x, b = blockIdx.y;
    const int q0 = qt * 8;

    const float4* ekb4 = (const float4*)(ek + (size_t)(b * 512) * 256);

    // prologue: stage eq (8x256 = 512 float4s), scale, ek tile 0
    if (t < 512) {
        const int row = t >> 6, c = t & 63;
        const float4 v = ((const float4*)(eq + (size_t)(b * 512 + q0) * 256))[row * 64 + c];
        *(float4*)&eq_lds[row * EQ_ST + 4 * c] = v;
    } else if (t < 768) {
        sc_lds[t - 512] = -2.f * scale[t - 512];
    }
    {
#pragma unroll
        for (int l = 0; l < 4; ++l) {
            const int row = w + 16 * l;
            const int cc = (lane + (row >> 2)) & 63;
            *(float4*)&ek_lds[row * EK_ST + 4 * cc] = ekb4[(size_t)row * 64 + lane];
        }
    }
    __syncthreads();

    const int d0 = 32 * oct + 8 * dd;       // this thread's 8-d subsector

    // ---- Phase A: 8 k-tiles ----
    for (int tt = 0; tt < 8; ++tt) {
        // T14: issue next tile's global loads FIRST (latency hides under compute)
        float4 g0, g1, g2, g3;
        if (tt < 7) {
            const float4* src = ekb4 + (size_t)(64 * (tt + 1)) * 64;
            g0 = src[(size_t)(w +  0) * 64 + lane];
            g1 = src[(size_t)(w + 16) * 64 + lane];
            g2 = src[(size_t)(w + 32) * 64 + lane];
            g3 = src[(size_t)(w + 48) * 64 + lane];
        }

        float acc[4][4];
#pragma unroll
        for (int i = 0; i < 4; ++i)
#pragma unroll
            for (int j = 0; j < 4; ++j) acc[i][j] = 0.f;

#pragma unroll
        for (int it = 0; it < 2; ++it) {
            const int d = d0 + 4 * it;
            const float4 sv = *(const float4*)&sc_lds[d];
            float4 qv[4], kv[4];
#pragma unroll
            for (int i = 0; i < 4; ++i)
                qv[i] = *(const float4*)&eq_lds[(4 * qh + i) * EQ_ST + d];
            const int cc = 4 * (((d >> 2) + kq) & 63);
#pragma unroll
            for (int j = 0; j < 4; ++j)
                kv[j] = *(const float4*)&ek_lds[(4 * kq + j) * EK_ST + cc];

#pragma unroll
            for (int i = 0; i < 4; ++i)
#pragma unroll
                for (int j = 0; j < 4; ++j) {
                    term2(sv.x, sv.y, qv[i].x, qv[i].y, kv[j].x, kv[j].y, acc[i][j]);
                    term2(sv.z, sv.w, qv[i].z, qv[i].w, kv[j].z, kv[j].w, acc[i][j]);
                }
        }

        // combine dd-subsectors in-register (lane^16, lane^32)
#pragma unroll
        for (int i = 0; i < 4; ++i)
#pragma unroll
            for (int j = 0; j < 4; ++j) {
                acc[i][j] += __shfl_xor(acc[i][j], 16);
                acc[i][j] += __shfl_xor(acc[i][j], 32);
            }

        if (dd == 0) {                      // lanes 0..15 hold full-octant sums
            float* ps = &pslot[oct * PSO_ST + (4 * qh) * PSQ_ST];
#pragma unroll
            for (int i = 0; i < 4; ++i) {
                float4 v; v.x = acc[i][0]; v.y = acc[i][1];
                v.z = acc[i][2]; v.w = acc[i][3];
                *(float4*)&ps[i * PSQ_ST + 4 * kq] = v;
            }
        }
        __syncthreads();                    // ek reads + pslot writes done

        if (tt < 7) {                       // ds_write the prefetched tile
#pragma unroll
            for (int l = 0; l < 4; ++l) {
                const int row = w + 16 * l;
                const int cc = (lane + (row >> 2)) & 63;
                const float4 g = (l == 0) ? g0 : (l == 1) ? g1 : (l == 2) ? g2 : g3;
                *(float4*)&ek_lds[row * EK_ST + 4 * cc] = g;
            }
        }
        if (t < 512) {                      // deterministic octant sum
            const int qrow = t >> 6, k = t & 63;
            float s = pslot[qrow * PSQ_ST + k];
#pragma unroll
            for (int o = 1; o < 8; ++o) s += pslot[o * PSO_ST + qrow * PSQ_ST + k];
            s_tile[qrow * SS_ST + 64 * tt + k] = s;
        }
        __syncthreads();                    // staged + combined
    }

    // ---- Phase B: softmax (waves 0..7, wave = q-row) ----
    if (w < 8) {
        float x[8];
        float m = -1e30f;
#pragma unroll
        for (int j = 0; j < 8; ++j) {
            x[j] = s_tile[w * SS_ST + 64 * j + lane];
            m = fmaxf(m, x[j]);
        }
#pragma unroll
        for (int off = 32; off; off >>= 1) m = fmaxf(m, __shfl_xor(m, off));

        float sum = 0.f;
#pragma unroll
        for (int j = 0; j < 8; ++j) { x[j] = fast_exp2((x[j] - m) * LOG2E); sum += x[j]; }
#pragma unroll
        for (int off = 32; off; off >>= 1) sum += __shfl_xor(sum, off);
        const float inv = fast_rcp(sum);

        float* arow = attn + (size_t)(b * 512 + q0 + w) * 512;
#pragma unroll
        for (int j = 0; j < 8; ++j) {
            s_tile[w * SS_ST + 64 * j + lane] = x[j];   // raw exp for PV
            arow[64 * j + lane] = x[j] * inv;
        }
        if (lane == 0) inv_lds[w] = inv;
    }
    __syncthreads();

    // ---- Phase C: PV, wave w owns k in [32w, 32w+32) ----
    float4 acc[8];
#pragma unroll
    for (int r = 0; r < 8; ++r) acc[r] = make_float4(0.f, 0.f, 0.f, 0.f);

    const float* vbase = value + (size_t)(b * 512 + 32 * w) * 256;
    for (int k4 = 0; k4 < 32; k4 += 4) {
        const float4 v0 = *(const float4*)&vbase[(k4 + 0) * 256 + lane * 4];
        const float4 v1 = *(const float4*)&vbase[(k4 + 1) * 256 + lane * 4];
        const float4 v2 = *(const float4*)&vbase[(k4 + 2) * 256 + lane * 4];
        const float4 v3 = *(const float4*)&vbase[(k4 + 3) * 256 + lane * 4];
#pragma unroll
        for (int r = 0; r < 8; ++r) {
            const float4 s4 = *(const float4*)&s_tile[r * SS_ST + 32 * w + k4];
            acc[r].x = fmaf(s4.x, v0.x, acc[r].x); acc[r].y = fmaf(s4.x, v0.y, acc[r].y);
            acc[r].z = fmaf(s4.x, v0.z, acc[r].z); acc[r].w = fmaf(s4.x, v0.w, acc[r].w);
            acc[r].x = fmaf(s4.y, v1.x, acc[r].x); acc[r].y = fmaf(s4.y, v1.y, acc[r].y);
            acc[r].z = fmaf(s4.y, v1.z, acc[r].z); acc[r].w = fmaf(s4.y, v1.w, acc[r].w);
            acc[r].x = fmaf(s4.z, v2.x, acc[r].x); acc[r].y = fmaf(s4.z, v2.y, acc[r].y);
            acc[r].z = fmaf(s4.z, v2.z, acc[r].z); acc[r].w = fmaf(s4.z, v2.w, acc[r].w);
            acc[r].x = fmaf(s4.w, v3.x, acc[r].x); acc[r].y = fmaf(s4.w, v3.y, acc[r].y);
            acc[r].z = fmaf(s4.w, v3.z, acc[r].z); acc[r].w = fmaf(s4.w, v3.w, acc[r].w);
        }
    }

    // ---- Phase D: tree reduce 16 -> 1 (red = ek_lds, 16640 >= 16384) ----
    float* red = ek_lds;
    if (w >= 8) {
#pragma unroll
        for (int r = 0; r < 8; ++r)
            *(float4*)&red[((w - 8) * 8 + r) * 256 + lane * 4] = acc[r];
    }
    __syncthreads();
    if (w < 8) {
#pragma unroll
        for (int r = 0; r < 8; ++r) {
            const float4 o = *(const float4*)&red[(w * 8 + r) * 256 + lane * 4];
            acc[r].x += o.x; acc[r].y += o.y; acc[r].z += o.z; acc[r].w += o.w;
        }
    }
    __syncthreads();
    if (w >= 4 && w < 8) {
#pragma unroll
        for (int r = 0; r < 8; ++r)
            *(float4*)&red[((w - 4) * 8 + r) * 256 + lane * 4] = acc[r];
    }
    __syncthreads();
    if (w < 4) {
#pragma unroll
        for (int r = 0; r < 8; ++r) {
            const float4 o = *(const float4*)&red[(w * 8 + r) * 256 + lane * 4];
            acc[r].x += o.x; acc[r].y += o.y; acc[r].z += o.z; acc[r].w += o.w;
        }
    }
    __syncthreads();
    if (w >= 2 && w < 4) {
#pragma unroll
        for (int r = 0; r < 8; ++r)
            *(float4*)&red[((w - 2) * 8 + r) * 256 + lane * 4] = acc[r];
    }
    __syncthreads();
    if (w < 2) {
#pragma unroll
        for (int r = 0; r < 8; ++r) {
            const float4 o = *(const float4*)&red[(w * 8 + r) * 256 + lane * 4];
            acc[r].x += o.x; acc[r].y += o.y; acc[r].z += o.z; acc[r].w += o.w;
        }
    }
    __syncthreads();
    if (w == 1) {
#pragma unroll
        for (int r = 0; r < 8; ++r)
            *(float4*)&red[r * 256 + lane * 4] = acc[r];
    }
    __syncthreads();
    if (w == 0) {
#pragma unroll
        for (int r = 0; r < 8; ++r) {
            const float4 o = *(const float4*)&red[r * 256 + lane * 4];
            const float iv = inv_lds[r];
            float4 res;
            res.x = (acc[r].x + o.x) * iv;
            res.y = (acc[r].y + o.y) * iv;
            res.z = (acc[r].z + o.z) * iv;
            res.w = (acc[r].w + o.w) * iv;
            *(float4*)&out[(size_t)(b * 512 + q0 + r) * 256 + lane * 4] = res;
        }
    }
}

extern "C" void kernel_launch(void* const* d_in, const int* in_sizes, int n_in,
                              void* d_out, int out_size, void* d_ws, size_t ws_size,
                              hipStream_t stream) {
    const float* query = (const float*)d_in[0];
    const float* value = (const float*)d_in[1];
    const float* Wq    = (const float*)d_in[2];
    const float* Wv    = (const float*)d_in[3];
    const float* scale = (const float*)d_in[4];

    float* out0 = (float*)d_out;                 // [4,512,256]
    float* attn = out0 + 4 * 512 * 256;          // [4,512,512]

    float* eq = (float*)d_ws;                    // [2048,256]
    float* ek = eq + 2048 * 256;                 // [2048,256]

    proj_kernel<<<512, 256, 0, stream>>>(query, value, Wq, Wv, eq, ek);
    fused_kernel<<<dim3(64, 4), 1024, 0, stream>>>(eq, ek, scale, value, attn, out0);
}

// Round 21
// 64.564 us; speedup vs baseline: 1.0814x; 1.0814x over previous
//
#include <hip/hip_runtime.h>

#define LOG2E 1.4426950408889634f
#define TWO_LOG2E 2.885390081777927f

__device__ __forceinline__ float fast_exp2(float x) { return __builtin_amdgcn_exp2f(x); }
__device__ __forceinline__ float fast_rcp(float x)  { return __builtin_amdgcn_rcpf(x); }

// paired-rcp: s0/A + s1/B with A=q0*k0+1, B=q1*k1+1
__device__ __forceinline__ void term2(float s0, float s1, float qx, float qy,
                                      float kx, float ky, float& acc) {
    const float A = fmaf(qx, kx, 1.f);
    const float B = fmaf(qy, ky, 1.f);
    acc = fmaf(fmaf(s1, A, s0 * B), fast_rcp(A * B), acc);
}

// ---------------------------------------------------------------------------
// K1: projections + exp transform. Blocks 0..255: eq[2048][256] (row-major).
// Blocks 256..511: ekT[b][256 d][512 k] TRANSPOSED (each thread owns column
// d = t for 8 k-rows -> 8 contiguous floats = two float4 stores).
// ---------------------------------------------------------------------------
__global__ __launch_bounds__(256) void proj_kernel(
    const float* __restrict__ query, const float* __restrict__ value,
    const float* __restrict__ Wq, const float* __restrict__ Wv,
    float* __restrict__ eq, float* __restrict__ ekT)
{
    __shared__ float in_lds[8 * 256];
    const int t = threadIdx.x;
    const int row0 = blockIdx.x * 8;
    const float* src; const float* W;
    if (row0 < 2048) { src = query + (size_t)row0 * 256; W = Wq; }
    else { src = value + (size_t)(row0 - 2048) * 256; W = Wv; }

    const float4* s4 = (const float4*)src;
    float4* l4 = (float4*)in_lds;
    l4[t] = s4[t];
    l4[t + 256] = s4[t + 256];
    __syncthreads();

    float acc[8];
#pragma unroll
    for (int r = 0; r < 8; ++r) acc[r] = 0.f;

    for (int d = 0; d < 256; d += 4) {
        const float w0 = W[(d + 0) * 256 + t];
        const float w1 = W[(d + 1) * 256 + t];
        const float w2 = W[(d + 2) * 256 + t];
        const float w3 = W[(d + 3) * 256 + t];
#pragma unroll
        for (int r = 0; r < 8; ++r) {
            const float4 v = *(const float4*)&in_lds[r * 256 + d];
            acc[r] = fmaf(v.x, w0, acc[r]);
            acc[r] = fmaf(v.y, w1, acc[r]);
            acc[r] = fmaf(v.z, w2, acc[r]);
            acc[r] = fmaf(v.w, w3, acc[r]);
        }
    }

    if (row0 < 2048) {
        float* dst = eq + (size_t)row0 * 256;
#pragma unroll
        for (int r = 0; r < 8; ++r) dst[r * 256 + t] = fast_exp2(acc[r] * TWO_LOG2E);
    } else {
        const int r0 = row0 - 2048;
        const int bb = r0 >> 9, kin = r0 & 511;
        float* dstT = ekT + (size_t)bb * 131072 + (size_t)t * 512 + kin;
        float4 v0, v1;
        v0.x = fast_exp2(acc[0] * TWO_LOG2E); v0.y = fast_exp2(acc[1] * TWO_LOG2E);
        v0.z = fast_exp2(acc[2] * TWO_LOG2E); v0.w = fast_exp2(acc[3] * TWO_LOG2E);
        v1.x = fast_exp2(acc[4] * TWO_LOG2E); v1.y = fast_exp2(acc[5] * TWO_LOG2E);
        v1.z = fast_exp2(acc[6] * TWO_LOG2E); v1.w = fast_exp2(acc[7] * TWO_LOG2E);
        *(float4*)dstT = v0;
        *(float4*)(dstT + 4) = v1;
    }
}

// ---------------------------------------------------------------------------
// K2: FUSED scores + softmax + PV, v8: k-side from GLOBAL (transposed ekT),
// ZERO barriers in the scores phase.
// Block = (b, 8 q-rows), 512 thr (8 waves), grid (64,4) = 256 blocks.
// Thread = (qg = w>>2: 4 q-rows, kg = (w&3)*64+lane: 2 k-cols), FULL 256 d.
// Per 4-d it: 4 q b128 (LDS broadcast) + 1 sc b128 + 4 global b64 (lanes
// 8B apart -> 512B coalesced, L2-resident ekT) + 16 term2 (320 VALU cyc).
// VALU:LDS ~ 10:1; k-path on the TA/L2 pipe -> pipes overlap, no staging,
// no pslot, no shfl, no barriers until softmax.
// Softmax/PV/tree-reduce = R13-proven 8-wave code (red standalone, 32KB).
// LDS ~58KB.
// ---------------------------------------------------------------------------
#define EQ_ST 260
#define SS_ST 520
__global__ __launch_bounds__(512, 2) void fused_kernel(
    const float* __restrict__ eq, const float* __restrict__ ekT,
    const float* __restrict__ scale, const float* __restrict__ value,
    float* __restrict__ attn, float* __restrict__ out)
{
    __shared__ float eq_lds[8 * EQ_ST];     // 8.3KB
    __shared__ float sc_lds[256];
    __shared__ float s_tile[8 * SS_ST];     // 16.6KB raw scores -> raw exp
    __shared__ float red[4 * 8 * 256];      // 32KB PV reduce buffer
    __shared__ float inv_lds[8];

    const int t = threadIdx.x;
    const int w = t >> 6, lane = t & 63;
    const int qg = w >> 2;                  // 0..1 (4 q-rows each)
    const int kg = ((w & 3) << 6) + lane;   // 0..255 (2 k-cols each)
    const int k0 = 2 * kg;
    const int qt = blockIdx.x, b = blockIdx.y;
    const int q0 = qt * 8;

    // prologue: stage eq (8x256 = 512 float4s, 1/thread) and scale
    {
        const int row = t >> 6, c = t & 63;
        const float4 v = ((const float4*)(eq + (size_t)(b * 512 + q0) * 256))[row * 64 + c];
        *(float4*)&eq_lds[row * EQ_ST + 4 * c] = v;
    }
    if (t < 256) sc_lds[t] = -2.f * scale[t];
    __syncthreads();

    // ---- Phase A: scores, full d per thread, NO barriers ----
    const float* ekTb = ekT + (size_t)b * 131072;
    const float* q0r = &eq_lds[(4 * qg + 0) * EQ_ST];
    const float* q1r = &eq_lds[(4 * qg + 1) * EQ_ST];
    const float* q2r = &eq_lds[(4 * qg + 2) * EQ_ST];
    const float* q3r = &eq_lds[(4 * qg + 3) * EQ_ST];

    float a00 = 0.f, a01 = 0.f, a10 = 0.f, a11 = 0.f;
    float a20 = 0.f, a21 = 0.f, a30 = 0.f, a31 = 0.f;

#pragma unroll 4
    for (int d = 0; d < 256; d += 4) {
        const float4 sv = *(const float4*)&sc_lds[d];
        const float4 qv0 = *(const float4*)&q0r[d];
        const float4 qv1 = *(const float4*)&q1r[d];
        const float4 qv2 = *(const float4*)&q2r[d];
        const float4 qv3 = *(const float4*)&q3r[d];
        const float2 k0v = *(const float2*)&ekTb[(size_t)(d + 0) * 512 + k0];
        const float2 k1v = *(const float2*)&ekTb[(size_t)(d + 1) * 512 + k0];
        const float2 k2v = *(const float2*)&ekTb[(size_t)(d + 2) * 512 + k0];
        const float2 k3v = *(const float2*)&ekTb[(size_t)(d + 3) * 512 + k0];

        // pairs (d,d+1) and (d+2,d+3); k-col 0 -> .x, k-col 1 -> .y
        term2(sv.x, sv.y, qv0.x, qv0.y, k0v.x, k1v.x, a00);
        term2(sv.z, sv.w, qv0.z, qv0.w, k2v.x, k3v.x, a00);
        term2(sv.x, sv.y, qv0.x, qv0.y, k0v.y, k1v.y, a01);
        term2(sv.z, sv.w, qv0.z, qv0.w, k2v.y, k3v.y, a01);

        term2(sv.x, sv.y, qv1.x, qv1.y, k0v.x, k1v.x, a10);
        term2(sv.z, sv.w, qv1.z, qv1.w, k2v.x, k3v.x, a10);
        term2(sv.x, sv.y, qv1.x, qv1.y, k0v.y, k1v.y, a11);
        term2(sv.z, sv.w, qv1.z, qv1.w, k2v.y, k3v.y, a11);

        term2(sv.x, sv.y, qv2.x, qv2.y, k0v.x, k1v.x, a20);
        term2(sv.z, sv.w, qv2.z, qv2.w, k2v.x, k3v.x, a20);
        term2(sv.x, sv.y, qv2.x, qv2.y, k0v.y, k1v.y, a21);
        term2(sv.z, sv.w, qv2.z, qv2.w, k2v.y, k3v.y, a21);

        term2(sv.x, sv.y, qv3.x, qv3.y, k0v.x, k1v.x, a30);
        term2(sv.z, sv.w, qv3.z, qv3.w, k2v.x, k3v.x, a30);
        term2(sv.x, sv.y, qv3.x, qv3.y, k0v.y, k1v.y, a31);
        term2(sv.z, sv.w, qv3.z, qv3.w, k2v.y, k3v.y, a31);
    }

    // write raw scores (float2 per q-row; lanes 8B apart -> 2-way banks, free)
    *(float2*)&s_tile[(4 * qg + 0) * SS_ST + k0] = make_float2(a00, a01);
    *(float2*)&s_tile[(4 * qg + 1) * SS_ST + k0] = make_float2(a10, a11);
    *(float2*)&s_tile[(4 * qg + 2) * SS_ST + k0] = make_float2(a20, a21);
    *(float2*)&s_tile[(4 * qg + 3) * SS_ST + k0] = make_float2(a30, a31);
    __syncthreads();

    // ---- Phase B: softmax (wave w = q-row w), attn write ----
    {
        float x[8];
        float m = -1e30f;
#pragma unroll
        for (int j = 0; j < 8; ++j) {
            x[j] = s_tile[w * SS_ST + 64 * j + lane];
            m = fmaxf(m, x[j]);
        }
#pragma unroll
        for (int off = 32; off; off >>= 1) m = fmaxf(m, __shfl_xor(m, off));

        float sum = 0.f;
#pragma unroll
        for (int j = 0; j < 8; ++j) { x[j] = fast_exp2((x[j] - m) * LOG2E); sum += x[j]; }
#pragma unroll
        for (int off = 32; off; off >>= 1) sum += __shfl_xor(sum, off);
        const float inv = fast_rcp(sum);

        float* arow = attn + (size_t)(b * 512 + q0 + w) * 512;
#pragma unroll
        for (int j = 0; j < 8; ++j) {
            s_tile[w * SS_ST + 64 * j + lane] = x[j];   // raw exp for PV
            arow[64 * j + lane] = x[j] * inv;
        }
        if (lane == 0) inv_lds[w] = inv;
    }
    __syncthreads();

    // ---- Phase C: PV, wave w owns k in [64w, 64w+64) ----
    float4 acc[8];
#pragma unroll
    for (int r = 0; r < 8; ++r) acc[r] = make_float4(0.f, 0.f, 0.f, 0.f);

    const float* vbase = value + (size_t)(b * 512 + 64 * w) * 256;
    for (int k4 = 0; k4 < 64; k4 += 4) {
        const float4 v0 = *(const float4*)&vbase[(k4 + 0) * 256 + lane * 4];
        const float4 v1 = *(const float4*)&vbase[(k4 + 1) * 256 + lane * 4];
        const float4 v2 = *(const float4*)&vbase[(k4 + 2) * 256 + lane * 4];
        const float4 v3 = *(const float4*)&vbase[(k4 + 3) * 256 + lane * 4];
#pragma unroll
        for (int r = 0; r < 8; ++r) {
            const float4 s4 = *(const float4*)&s_tile[r * SS_ST + 64 * w + k4];
            acc[r].x = fmaf(s4.x, v0.x, acc[r].x); acc[r].y = fmaf(s4.x, v0.y, acc[r].y);
            acc[r].z = fmaf(s4.x, v0.z, acc[r].z); acc[r].w = fmaf(s4.x, v0.w, acc[r].w);
            acc[r].x = fmaf(s4.y, v1.x, acc[r].x); acc[r].y = fmaf(s4.y, v1.y, acc[r].y);
            acc[r].z = fmaf(s4.y, v1.z, acc[r].z); acc[r].w = fmaf(s4.y, v1.w, acc[r].w);
            acc[r].x = fmaf(s4.z, v2.x, acc[r].x); acc[r].y = fmaf(s4.z, v2.y, acc[r].y);
            acc[r].z = fmaf(s4.z, v2.z, acc[r].z); acc[r].w = fmaf(s4.z, v2.w, acc[r].w);
            acc[r].x = fmaf(s4.w, v3.x, acc[r].x); acc[r].y = fmaf(s4.w, v3.y, acc[r].y);
            acc[r].z = fmaf(s4.w, v3.z, acc[r].z); acc[r].w = fmaf(s4.w, v3.w, acc[r].w);
        }
    }

    // ---- Phase D: tree reduce 8 -> 1 ----
    if (w >= 4) {
#pragma unroll
        for (int r = 0; r < 8; ++r)
            *(float4*)&red[((w - 4) * 8 + r) * 256 + lane * 4] = acc[r];
    }
    __syncthreads();
    if (w < 4) {
#pragma unroll
        for (int r = 0; r < 8; ++r) {
            const float4 o = *(const float4*)&red[(w * 8 + r) * 256 + lane * 4];
            acc[r].x += o.x; acc[r].y += o.y; acc[r].z += o.z; acc[r].w += o.w;
        }
    }
    __syncthreads();
    if (w >= 2 && w < 4) {
#pragma unroll
        for (int r = 0; r < 8; ++r)
            *(float4*)&red[((w - 2) * 8 + r) * 256 + lane * 4] = acc[r];
    }
    __syncthreads();
    if (w < 2) {
#pragma unroll
        for (int r = 0; r < 8; ++r) {
            const float4 o = *(const float4*)&red[(w * 8 + r) * 256 + lane * 4];
            acc[r].x += o.x; acc[r].y += o.y; acc[r].z += o.z; acc[r].w += o.w;
        }
    }
    __syncthreads();
    if (w == 1) {
#pragma unroll
        for (int r = 0; r < 8; ++r)
            *(float4*)&red[r * 256 + lane * 4] = acc[r];
    }
    __syncthreads();
    if (w == 0) {
#pragma unroll
        for (int r = 0; r < 8; ++r) {
            const float4 o = *(const float4*)&red[r * 256 + lane * 4];
            const float iv = inv_lds[r];
            float4 res;
            res.x = (acc[r].x + o.x) * iv;
            res.y = (acc[r].y + o.y) * iv;
            res.z = (acc[r].z + o.z) * iv;
            res.w = (acc[r].w + o.w) * iv;
            *(float4*)&out[(size_t)(b * 512 + q0 + r) * 256 + lane * 4] = res;
        }
    }
}

extern "C" void kernel_launch(void* const* d_in, const int* in_sizes, int n_in,
                              void* d_out, int out_size, void* d_ws, size_t ws_size,
                              hipStream_t stream) {
    const float* query = (const float*)d_in[0];
    const float* value = (const float*)d_in[1];
    const float* Wq    = (const float*)d_in[2];
    const float* Wv    = (const float*)d_in[3];
    const float* scale = (const float*)d_in[4];

    float* out0 = (float*)d_out;                 // [4,512,256]
    float* attn = out0 + 4 * 512 * 256;          // [4,512,512]

    float* eq  = (float*)d_ws;                   // [2048,256]
    float* ekT = eq + 2048 * 256;                // [4,256,512] transposed

    proj_kernel<<<512, 256, 0, stream>>>(query, value, Wq, Wv, eq, ekT);
    fused_kernel<<<dim3(64, 4), 512, 0, stream>>>(eq, ekT, scale, value, attn, out0);
}

// Round 22
// 63.702 us; speedup vs baseline: 1.0960x; 1.0135x over previous
//
#include <hip/hip_runtime.h>

#define LOG2E 1.4426950408889634f
#define TWO_LOG2E 2.885390081777927f

__device__ __forceinline__ float fast_exp2(float x) { return __builtin_amdgcn_exp2f(x); }
__device__ __forceinline__ float fast_rcp(float x)  { return __builtin_amdgcn_rcpf(x); }

// paired-rcp: s0/A + s1/B with A=q0*k0+1, B=q1*k1+1
__device__ __forceinline__ void term2(float s0, float s1, float qx, float qy,
                                      float kx, float ky, float& acc) {
    const float A = fmaf(qx, kx, 1.f);
    const float B = fmaf(qy, ky, 1.f);
    acc = fmaf(fmaf(s1, A, s0 * B), fast_rcp(A * B), acc);
}

// ---------------------------------------------------------------------------
// K1: projections + exp transform. Blocks 0..255: eq[2048][256] (row-major).
// Blocks 256..511: ekT[b][256 d][512 k] TRANSPOSED.
// ---------------------------------------------------------------------------
__global__ __launch_bounds__(256) void proj_kernel(
    const float* __restrict__ query, const float* __restrict__ value,
    const float* __restrict__ Wq, const float* __restrict__ Wv,
    float* __restrict__ eq, float* __restrict__ ekT)
{
    __shared__ float in_lds[8 * 256];
    const int t = threadIdx.x;
    const int row0 = blockIdx.x * 8;
    const float* src; const float* W;
    if (row0 < 2048) { src = query + (size_t)row0 * 256; W = Wq; }
    else { src = value + (size_t)(row0 - 2048) * 256; W = Wv; }

    const float4* s4 = (const float4*)src;
    float4* l4 = (float4*)in_lds;
    l4[t] = s4[t];
    l4[t + 256] = s4[t + 256];
    __syncthreads();

    float acc[8];
#pragma unroll
    for (int r = 0; r < 8; ++r) acc[r] = 0.f;

    for (int d = 0; d < 256; d += 4) {
        const float w0 = W[(d + 0) * 256 + t];
        const float w1 = W[(d + 1) * 256 + t];
        const float w2 = W[(d + 2) * 256 + t];
        const float w3 = W[(d + 3) * 256 + t];
#pragma unroll
        for (int r = 0; r < 8; ++r) {
            const float4 v = *(const float4*)&in_lds[r * 256 + d];
            acc[r] = fmaf(v.x, w0, acc[r]);
            acc[r] = fmaf(v.y, w1, acc[r]);
            acc[r] = fmaf(v.z, w2, acc[r]);
            acc[r] = fmaf(v.w, w3, acc[r]);
        }
    }

    if (row0 < 2048) {
        float* dst = eq + (size_t)row0 * 256;
#pragma unroll
        for (int r = 0; r < 8; ++r) dst[r * 256 + t] = fast_exp2(acc[r] * TWO_LOG2E);
    } else {
        const int r0 = row0 - 2048;
        const int bb = r0 >> 9, kin = r0 & 511;
        float* dstT = ekT + (size_t)bb * 131072 + (size_t)t * 512 + kin;
        float4 v0, v1;
        v0.x = fast_exp2(acc[0] * TWO_LOG2E); v0.y = fast_exp2(acc[1] * TWO_LOG2E);
        v0.z = fast_exp2(acc[2] * TWO_LOG2E); v0.w = fast_exp2(acc[3] * TWO_LOG2E);
        v1.x = fast_exp2(acc[4] * TWO_LOG2E); v1.y = fast_exp2(acc[5] * TWO_LOG2E);
        v1.z = fast_exp2(acc[6] * TWO_LOG2E); v1.w = fast_exp2(acc[7] * TWO_LOG2E);
        *(float4*)dstT = v0;
        *(float4*)(dstT + 4) = v1;
    }
}

// ---------------------------------------------------------------------------
// K2: FUSED scores + softmax + PV, v9 = v8 + MANUAL SOFTWARE PIPELINE.
// v8 measured: VGPR 52 (compiler issued loads just-in-time), VALUBusy 50%,
// fused 47us vs ~20us of pipe work -> dependency-stall-bound. Fix: prefetch
// iteration d+4's loads (4 k-float2 global + 4 q-float4 + sc LDS) into named
// registers while computing iteration d. launch_bounds(512,2) keeps the
// VGPR cap at 128 so the rotation fits.
// Structure otherwise identical to v8 (0 bank conflicts, refchecked).
// ---------------------------------------------------------------------------
#define EQ_ST 260
#define SS_ST 520
__global__ __launch_bounds__(512, 2) void fused_kernel(
    const float* __restrict__ eq, const float* __restrict__ ekT,
    const float* __restrict__ scale, const float* __restrict__ value,
    float* __restrict__ attn, float* __restrict__ out)
{
    __shared__ float eq_lds[8 * EQ_ST];     // 8.3KB
    __shared__ float sc_lds[256];
    __shared__ float s_tile[8 * SS_ST];     // 16.6KB raw scores -> raw exp
    __shared__ float red[4 * 8 * 256];      // 32KB PV reduce buffer
    __shared__ float inv_lds[8];

    const int t = threadIdx.x;
    const int w = t >> 6, lane = t & 63;
    const int qg = w >> 2;                  // 0..1 (4 q-rows each)
    const int kg = ((w & 3) << 6) + lane;   // 0..255 (2 k-cols each)
    const int k0 = 2 * kg;
    const int qt = blockIdx.x, b = blockIdx.y;
    const int q0 = qt * 8;

    // prologue: stage eq (8x256 = 512 float4s, 1/thread) and scale
    {
        const int row = t >> 6, c = t & 63;
        const float4 v = ((const float4*)(eq + (size_t)(b * 512 + q0) * 256))[row * 64 + c];
        *(float4*)&eq_lds[row * EQ_ST + 4 * c] = v;
    }
    if (t < 256) sc_lds[t] = -2.f * scale[t];
    __syncthreads();

    // ---- Phase A: scores, full d per thread, NO barriers, pipelined ----
    const float* ekTb = ekT + (size_t)b * 131072;
    const float* q0r = &eq_lds[(4 * qg + 0) * EQ_ST];
    const float* q1r = &eq_lds[(4 * qg + 1) * EQ_ST];
    const float* q2r = &eq_lds[(4 * qg + 2) * EQ_ST];
    const float* q3r = &eq_lds[(4 * qg + 3) * EQ_ST];

    float a00 = 0.f, a01 = 0.f, a10 = 0.f, a11 = 0.f;
    float a20 = 0.f, a21 = 0.f, a30 = 0.f, a31 = 0.f;

    // preload iteration d=0
    float4 sv  = *(const float4*)&sc_lds[0];
    float4 qv0 = *(const float4*)&q0r[0];
    float4 qv1 = *(const float4*)&q1r[0];
    float4 qv2 = *(const float4*)&q2r[0];
    float4 qv3 = *(const float4*)&q3r[0];
    float2 k0v = *(const float2*)&ekTb[(size_t)0 * 512 + k0];
    float2 k1v = *(const float2*)&ekTb[(size_t)1 * 512 + k0];
    float2 k2v = *(const float2*)&ekTb[(size_t)2 * 512 + k0];
    float2 k3v = *(const float2*)&ekTb[(size_t)3 * 512 + k0];

#pragma unroll 4
    for (int d = 0; d < 256; d += 4) {
        // rotate current into locals
        const float4 csv = sv, c0 = qv0, c1 = qv1, c2 = qv2, c3 = qv3;
        const float2 ck0 = k0v, ck1 = k1v, ck2 = k2v, ck3 = k3v;

        // prefetch iteration d+4 (in flight during the 16 term2 below)
        if (d < 252) {
            const int dn = d + 4;
            sv  = *(const float4*)&sc_lds[dn];
            qv0 = *(const float4*)&q0r[dn];
            qv1 = *(const float4*)&q1r[dn];
            qv2 = *(const float4*)&q2r[dn];
            qv3 = *(const float4*)&q3r[dn];
            k0v = *(const float2*)&ekTb[(size_t)(dn + 0) * 512 + k0];
            k1v = *(const float2*)&ekTb[(size_t)(dn + 1) * 512 + k0];
            k2v = *(const float2*)&ekTb[(size_t)(dn + 2) * 512 + k0];
            k3v = *(const float2*)&ekTb[(size_t)(dn + 3) * 512 + k0];
        }

        // pairs (d,d+1) and (d+2,d+3); k-col 0 -> .x, k-col 1 -> .y
        term2(csv.x, csv.y, c0.x, c0.y, ck0.x, ck1.x, a00);
        term2(csv.z, csv.w, c0.z, c0.w, ck2.x, ck3.x, a00);
        term2(csv.x, csv.y, c0.x, c0.y, ck0.y, ck1.y, a01);
        term2(csv.z, csv.w, c0.z, c0.w, ck2.y, ck3.y, a01);

        term2(csv.x, csv.y, c1.x, c1.y, ck0.x, ck1.x, a10);
        term2(csv.z, csv.w, c1.z, c1.w, ck2.x, ck3.x, a10);
        term2(csv.x, csv.y, c1.x, c1.y, ck0.y, ck1.y, a11);
        term2(csv.z, csv.w, c1.z, c1.w, ck2.y, ck3.y, a11);

        term2(csv.x, csv.y, c2.x, c2.y, ck0.x, ck1.x, a20);
        term2(csv.z, csv.w, c2.z, c2.w, ck2.x, ck3.x, a20);
        term2(csv.x, csv.y, c2.x, c2.y, ck0.y, ck1.y, a21);
        term2(csv.z, csv.w, c2.z, c2.w, ck2.y, ck3.y, a21);

        term2(csv.x, csv.y, c3.x, c3.y, ck0.x, ck1.x, a30);
        term2(csv.z, csv.w, c3.z, c3.w, ck2.x, ck3.x, a30);
        term2(csv.x, csv.y, c3.x, c3.y, ck0.y, ck1.y, a31);
        term2(csv.z, csv.w, c3.z, c3.w, ck2.y, ck3.y, a31);
    }

    // write raw scores (float2 per q-row; lanes 8B apart -> 2-way banks, free)
    *(float2*)&s_tile[(4 * qg + 0) * SS_ST + k0] = make_float2(a00, a01);
    *(float2*)&s_tile[(4 * qg + 1) * SS_ST + k0] = make_float2(a10, a11);
    *(float2*)&s_tile[(4 * qg + 2) * SS_ST + k0] = make_float2(a20, a21);
    *(float2*)&s_tile[(4 * qg + 3) * SS_ST + k0] = make_float2(a30, a31);
    __syncthreads();

    // ---- Phase B: softmax (wave w = q-row w), attn write ----
    {
        float x[8];
        float m = -1e30f;
#pragma unroll
        for (int j = 0; j < 8; ++j) {
            x[j] = s_tile[w * SS_ST + 64 * j + lane];
            m = fmaxf(m, x[j]);
        }
#pragma unroll
        for (int off = 32; off; off >>= 1) m = fmaxf(m, __shfl_xor(m, off));

        float sum = 0.f;
#pragma unroll
        for (int j = 0; j < 8; ++j) { x[j] = fast_exp2((x[j] - m) * LOG2E); sum += x[j]; }
#pragma unroll
        for (int off = 32; off; off >>= 1) sum += __shfl_xor(sum, off);
        const float inv = fast_rcp(sum);

        float* arow = attn + (size_t)(b * 512 + q0 + w) * 512;
#pragma unroll
        for (int j = 0; j < 8; ++j) {
            s_tile[w * SS_ST + 64 * j + lane] = x[j];   // raw exp for PV
            arow[64 * j + lane] = x[j] * inv;
        }
        if (lane == 0) inv_lds[w] = inv;
    }
    __syncthreads();

    // ---- Phase C: PV, wave w owns k in [64w, 64w+64) ----
    float4 acc[8];
#pragma unroll
    for (int r = 0; r < 8; ++r) acc[r] = make_float4(0.f, 0.f, 0.f, 0.f);

    const float* vbase = value + (size_t)(b * 512 + 64 * w) * 256;
    for (int k4 = 0; k4 < 64; k4 += 4) {
        const float4 v0 = *(const float4*)&vbase[(k4 + 0) * 256 + lane * 4];
        const float4 v1 = *(const float4*)&vbase[(k4 + 1) * 256 + lane * 4];
        const float4 v2 = *(const float4*)&vbase[(k4 + 2) * 256 + lane * 4];
        const float4 v3 = *(const float4*)&vbase[(k4 + 3) * 256 + lane * 4];
#pragma unroll
        for (int r = 0; r < 8; ++r) {
            const float4 s4 = *(const float4*)&s_tile[r * SS_ST + 64 * w + k4];
            acc[r].x = fmaf(s4.x, v0.x, acc[r].x); acc[r].y = fmaf(s4.x, v0.y, acc[r].y);
            acc[r].z = fmaf(s4.x, v0.z, acc[r].z); acc[r].w = fmaf(s4.x, v0.w, acc[r].w);
            acc[r].x = fmaf(s4.y, v1.x, acc[r].x); acc[r].y = fmaf(s4.y, v1.y, acc[r].y);
            acc[r].z = fmaf(s4.y, v1.z, acc[r].z); acc[r].w = fmaf(s4.y, v1.w, acc[r].w);
            acc[r].x = fmaf(s4.z, v2.x, acc[r].x); acc[r].y = fmaf(s4.z, v2.y, acc[r].y);
            acc[r].z = fmaf(s4.z, v2.z, acc[r].z); acc[r].w = fmaf(s4.z, v2.w, acc[r].w);
            acc[r].x = fmaf(s4.w, v3.x, acc[r].x); acc[r].y = fmaf(s4.w, v3.y, acc[r].y);
            acc[r].z = fmaf(s4.w, v3.z, acc[r].z); acc[r].w = fmaf(s4.w, v3.w, acc[r].w);
        }
    }

    // ---- Phase D: tree reduce 8 -> 1 ----
    if (w >= 4) {
#pragma unroll
        for (int r = 0; r < 8; ++r)
            *(float4*)&red[((w - 4) * 8 + r) * 256 + lane * 4] = acc[r];
    }
    __syncthreads();
    if (w < 4) {
#pragma unroll
        for (int r = 0; r < 8; ++r) {
            const float4 o = *(const float4*)&red[(w * 8 + r) * 256 + lane * 4];
            acc[r].x += o.x; acc[r].y += o.y; acc[r].z += o.z; acc[r].w += o.w;
        }
    }
    __syncthreads();
    if (w >= 2 && w < 4) {
#pragma unroll
        for (int r = 0; r < 8; ++r)
            *(float4*)&red[((w - 2) * 8 + r) * 256 + lane * 4] = acc[r];
    }
    __syncthreads();
    if (w < 2) {
#pragma unroll
        for (int r = 0; r < 8; ++r) {
            const float4 o = *(const float4*)&red[(w * 8 + r) * 256 + lane * 4];
            acc[r].x += o.x; acc[r].y += o.y; acc[r].z += o.z; acc[r].w += o.w;
        }
    }
    __syncthreads();
    if (w == 1) {
#pragma unroll
        for (int r = 0; r < 8; ++r)
            *(float4*)&red[r * 256 + lane * 4] = acc[r];
    }
    __syncthreads();
    if (w == 0) {
#pragma unroll
        for (int r = 0; r < 8; ++r) {
            const float4 o = *(const float4*)&red[r * 256 + lane * 4];
            const float iv = inv_lds[r];
            float4 res;
            res.x = (acc[r].x + o.x) * iv;
            res.y = (acc[r].y + o.y) * iv;
            res.z = (acc[r].z + o.z) * iv;
            res.w = (acc[r].w + o.w) * iv;
            *(float4*)&out[(size_t)(b * 512 + q0 + r) * 256 + lane * 4] = res;
        }
    }
}

extern "C" void kernel_launch(void* const* d_in, const int* in_sizes, int n_in,
                              void* d_out, int out_size, void* d_ws, size_t ws_size,
                              hipStream_t stream) {
    const float* query = (const float*)d_in[0];
    const float* value = (const float*)d_in[1];
    const float* Wq    = (const float*)d_in[2];
    const float* Wv    = (const float*)d_in[3];
    const float* scale = (const float*)d_in[4];

    float* out0 = (float*)d_out;                 // [4,512,256]
    float* attn = out0 + 4 * 512 * 256;          // [4,512,512]

    float* eq  = (float*)d_ws;                   // [2048,256]
    float* ekT = eq + 2048 * 256;                // [4,256,512] transposed

    proj_kernel<<<512, 256, 0, stream>>>(query, value, Wq, Wv, eq, ekT);
    fused_kernel<<<dim3(64, 4), 512, 0, stream>>>(eq, ekT, scale, value, attn, out0);
}